// Round 19
// baseline (778.085 us; speedup 1.0000x reference)
//
#include <hip/hip_runtime.h>
#include <hip/hip_bf16.h>
#include <math.h>

#define N_NODES 50000
#define N_EDGES 800000
#define N_CHUNKS 50000          // 16-edge work units
#define CLAMP_V 5.0f

typedef short short8 __attribute__((ext_vector_type(8)));
typedef short short4v __attribute__((ext_vector_type(4)));
typedef float f32x4  __attribute__((ext_vector_type(4)));

static __device__ inline short f2bf(float x) {
    __hip_bfloat16 h = __float2bfloat16(x);   // RNE
    return __builtin_bit_cast(short, h);
}
static __device__ inline float bf2f(short s) {
    unsigned u = ((unsigned)(unsigned short)s) << 16;
    return __builtin_bit_cast(float, u);
}

// ---------------- Kernel 1: Q/K/V node projections (unchanged, proven) ----------------
__global__ __launch_bounds__(256) void qkv_kernel(
    const float* __restrict__ x,
    const float* __restrict__ WQ, const float* __restrict__ bQ,
    const float* __restrict__ WK, const float* __restrict__ bK,
    const float* __restrict__ WV, const float* __restrict__ bV,
    float* __restrict__ Q, float* __restrict__ K, float* __restrict__ V)
{
    const int t = threadIdx.x;
    const int c = t & 63;
    const int nl = t >> 6;
    const int base = blockIdx.x * 16;

    float accQ[4], accK[4], accV[4];
    int nodes[4];
#pragma unroll
    for (int j = 0; j < 4; ++j) {
        nodes[j] = base + j * 4 + nl;
        accQ[j] = bQ[c]; accK[j] = bK[c]; accV[j] = bV[c];
    }
    for (int k = 0; k < 64; ++k) {
        const float wq = WQ[k * 64 + c];
        const float wk = WK[k * 64 + c];
        const float wv = WV[k * 64 + c];
#pragma unroll
        for (int j = 0; j < 4; ++j) {
            const float xv = x[nodes[j] * 64 + k];
            accQ[j] += xv * wq;
            accK[j] += xv * wk;
            accV[j] += xv * wv;
        }
    }
#pragma unroll
    for (int j = 0; j < 4; ++j) {
        const int n = nodes[j];
        Q[n * 64 + c] = accQ[j];
        K[n * 64 + c] = accK[j];
        V[n * 64 + c] = accV[j];
    }
}

// ---------------- Kernel 2: fused E-GEMM + score + denom + numerator ----------------
// R18 arithmetic/LDS/fence structure EXACTLY, plus wave-level dynamic work
// queue: each wave atomically fetches its next 16-edge chunk one iteration
// ahead (latency hidden under convert+MFMA). Removes the 17-vs-16 iteration
// static imbalance (12500 block-iters not divisible by 768 blocks) — worth
// ~6% of edge time. Deterministic: each chunk processed exactly once.
__global__ __launch_bounds__(256, 3) void edge_kernel(
    const float* __restrict__ edge_attr,
    const int* __restrict__ src_idx, const int* __restrict__ dst_idx,
    const float* __restrict__ WE, const float* __restrict__ bE,
    const float* __restrict__ Aw,
    const float* __restrict__ Qn, const float* __restrict__ Kn,
    const float* __restrict__ Vn, const float* __restrict__ VeRow,
    float* __restrict__ wE_out, float* __restrict__ denom,
    float* __restrict__ wV_num, int* __restrict__ wq_counter)
{
    // [0,16K)=B_hi  [16K,32K)=B_lo  [32K, +4*4160)=E^T bf16 bufs
    __shared__ __align__(16) char raw[49408];
    __shared__ float bEs[128];

    short8* Bhi = (short8*)raw;                  // [(ct*2+kh)*64 + lane]
    short8* Blo = (short8*)(raw + 16384);

    const int t = threadIdx.x;
    const int wave = t >> 6;
    const int lane = t & 63;

    // ---- init: bf16 hi/lo B-fragments from global WE
    short* BhiE = (short*)raw;
    short* BloE = (short*)(raw + 16384);
    for (int i = t; i < 8192; i += 256) {
        const int j  = i & 7;
        const int ln = (i >> 3) & 63;
        const int kh = (i >> 9) & 1;
        const int ct = i >> 10;
        const int k   = kh * 32 + ((ln >> 4) << 3) + j;
        const int col = (ct << 4) + (ln & 15);
        const float w = WE[k * 128 + col];
        const short hb = f2bf(w);
        BhiE[i] = hb;
        BloE[i] = f2bf(w - bf2f(hb));
    }
    if (t < 128) bEs[t] = bE[t];
    __syncthreads();

    unsigned short* Eb = (unsigned short*)(raw + 32768 + wave * 4160);

    const int h    = lane >> 3;
    const int kk   = lane & 7;
    const int g    = lane >> 4;
    const int c4   = lane & 15;
    const int h16k = (h << 4) + kk;
    const int ewbase = (h16k << 4) + (h << 2);          // col1 = h16k
    const int ebbase = ((h16k + 8) << 4) + (h << 2);    // col2 = h16k+8

    // loop-invariant weights in registers (global reads, once, L2-hot)
    float veR[8], awR[8];
#pragma unroll
    for (int dd = 0; dd < 8; ++dd) {
        veR[dd] = VeRow[dd * 64 + lane];
        awR[dd] = Aw[dd * 8 + h];
    }

    // ---- dynamic work queue: fetch one chunk (16 edges) per wave-iteration
    auto fetch_chunk = [&]() -> int {
        int v = 0;
        if (lane == 0) v = atomicAdd(wq_counter, 1);
        return __builtin_amdgcn_readfirstlane(__shfl(v, 0));
    };

    // pipeline state: current A-raw + indices; next A-raw + indices
    float4 arC[4], arN[4];
    int seC[16], deC[16], seN[16], deN[16];

    // ---- prologue: fetch first chunk and its data
    int cC = fetch_chunk();
    if (cC >= N_CHUNKS) return;
    {
        const int ebase0 = cC << 4;
#pragma unroll
        for (int p = 0; p < 2; ++p) {
            const float* srcp = edge_attr + (size_t)(ebase0 + c4) * 64 + p * 32 + (g << 3);
            arC[2 * p]     = *(const float4*)srcp;
            arC[2 * p + 1] = *(const float4*)(srcp + 4);
        }
#pragma unroll
        for (int r = 0; r < 16; ++r) {
            seC[r] = src_idx[ebase0 + r];
            deC[r] = dst_idx[ebase0 + r];
        }
    }

    while (true) {
        const int ebaseC = cC << 4;
        // ---- fetch NEXT chunk id (latency hidden under convert+MFMA below)
        const int cN     = fetch_chunk();
        const int cNc    = (cN < N_CHUNKS) ? cN : 0;    // clamped (unused at tail)
        const int ebaseN = cNc << 4;

        // ---- convert A(cur) -> bf16 hi/lo (arC landed long ago; no wait)
        short8 ah[2], al[2];
#pragma unroll
        for (int p = 0; p < 2; ++p) {
            const float xv[8] = {arC[2*p].x, arC[2*p].y, arC[2*p].z, arC[2*p].w,
                                 arC[2*p+1].x, arC[2*p+1].y, arC[2*p+1].z, arC[2*p+1].w};
#pragma unroll
            for (int j = 0; j < 8; ++j) {
                const short hb = f2bf(xv[j]);
                ah[p][j] = hb;
                al[p][j] = f2bf(xv[j] - bf2f(hb));
            }
        }

        // ---- next-chunk index scalar loads (land during MFMA)
#pragma unroll
        for (int r = 0; r < 16; ++r) {
            seN[r] = src_idx[ebaseN + r];
            deN[r] = dst_idx[ebaseN + r];
        }

        // ---- gathers for CURRENT chunk (consumed in score phase)
        float vv[16], kv[16], qv[16];
#pragma unroll
        for (int r = 0; r < 16; ++r) vv[r] = Vn[seC[r] * 64 + lane];
#pragma unroll
        for (int r = 0; r < 16; ++r) {
            kv[r] = Kn[seC[r] * 64 + lane];
            qv[r] = Qn[deC[r] * 64 + lane];
        }

        // ---- A(next) raw loads: issued last, consumed at body end
#pragma unroll
        for (int p = 0; p < 2; ++p) {
            const float* srcp = edge_attr + (size_t)(ebaseN + c4) * 64 + p * 32 + (g << 3);
            arN[2 * p]     = *(const float4*)srcp;
            arN[2 * p + 1] = *(const float4*)(srcp + 4);
        }

        // ---- MFMA (3-product bf16 split — full precision)
        f32x4 acc[8] = {};
        __builtin_amdgcn_s_setprio(1);
#pragma unroll
        for (int kh = 0; kh < 2; ++kh) {
#pragma unroll
            for (int ct = 0; ct < 8; ++ct) {
                const short8 bh = Bhi[(ct * 2 + kh) * 64 + lane];
                const short8 bl = Blo[(ct * 2 + kh) * 64 + lane];
                acc[ct] = __builtin_amdgcn_mfma_f32_16x16x32_bf16(ah[kh], bh, acc[ct], 0, 0, 0);
                acc[ct] = __builtin_amdgcn_mfma_f32_16x16x32_bf16(al[kh], bh, acc[ct], 0, 0, 0);
                acc[ct] = __builtin_amdgcn_mfma_f32_16x16x32_bf16(ah[kh], bl, acc[ct], 0, 0, 0);
            }
        }
        __builtin_amdgcn_s_setprio(0);

        // ---- E^T write: ALL lanes, bf16 packed b64, then ONE fence
#pragma unroll
        for (int ct = 0; ct < 8; ++ct) {
            const int col = (ct << 4) + c4;
            const float b = bEs[col];
            short4v pk;
#pragma unroll
            for (int rr = 0; rr < 4; ++rr) pk[rr] = f2bf(acc[ct][rr] + b);
            *(short4v*)(Eb + (col << 4) + (ct << 2) + (g << 2)) = pk;
        }
        __asm__ volatile("s_waitcnt lgkmcnt(0)" ::: "memory");
        __builtin_amdgcn_sched_barrier(0);

        // ---- score: 16 independent edge chains (no intervening fences)
#pragma unroll
        for (int idx = 0; idx < 16; ++idx) {
            const int e = ebaseC + idx;
            const int d = deC[idx];
            const float kq = kv[idx] + qv[idx];
            const float ew = bf2f((short)Eb[ewbase + idx]);
            const float eb = bf2f((short)Eb[ebbase + idx]);
            float sc = kq * ew;
            sc = copysignf(sqrtf(fabsf(sc)), sc) + eb;  // signed sqrt
            wE_out[(size_t)e * 64 + lane] = sc;

            // broadcast e_t[h,dd] once; feed BOTH rsum and the logit
            float rsum = 0.f, pp = 0.f;
#pragma unroll
            for (int dd = 0; dd < 8; ++dd) {
                const float etd = __shfl(sc, (lane & 56) + dd);  // e_t[h,dd]
                rsum += etd * veR[dd];                           // VeRow[dd,h,kk]
                pp   += etd * awR[dd];                           // Aw[dd,h]
            }
            pp = fminf(fmaxf(pp, -CLAMP_V), CLAMP_V);
            const float ex = __expf(pp);
            if (kk == 0) unsafeAtomicAdd(&denom[d * 8 + h], ex);
            unsafeAtomicAdd(&wV_num[(size_t)d * 64 + lane],
                            ex * (vv[idx] + rsum));
        }
        __builtin_amdgcn_sched_barrier(0);   // next iter's E^T writes stay below

        if (cN >= N_CHUNKS) break;
        // ---- rotate pipeline state (arN landed during MFMA+score)
        cC = cN;
#pragma unroll
        for (int p = 0; p < 4; ++p) arC[p] = arN[p];
#pragma unroll
        for (int r = 0; r < 16; ++r) { seC[r] = seN[r]; deC[r] = deN[r]; }
    }
}

// ---------------- Kernel 3: finalize — wV = numer / denom (float4) ----------------
__global__ __launch_bounds__(256) void finalize_kernel(
    const float* __restrict__ denom, float* __restrict__ wV)
{
    const int i4 = blockIdx.x * 256 + threadIdx.x;  // 3125 blocks * 256 = 800K float4
    const int base = i4 << 2;                       // 4 consecutive floats, same h-block
    const int n = base >> 6;
    const int h = (base >> 3) & 7;
    const float inv = 1.0f / (denom[n * 8 + h] + 1e-16f);
    float4 v = *(float4*)(wV + base);
    v.x *= inv; v.y *= inv; v.z *= inv; v.w *= inv;
    *(float4*)(wV + base) = v;
}

extern "C" void kernel_launch(void* const* d_in, const int* in_sizes, int n_in,
                              void* d_out, int out_size, void* d_ws, size_t ws_size,
                              hipStream_t stream) {
    const float* x         = (const float*)d_in[0];
    const float* edge_attr = (const float*)d_in[1];
    const int*   ei        = (const int*)  d_in[2];
    const float* WQ = (const float*)d_in[3];
    const float* bQ = (const float*)d_in[4];
    const float* WK = (const float*)d_in[5];
    const float* bK = (const float*)d_in[6];
    const float* WE = (const float*)d_in[7];
    const float* bE = (const float*)d_in[8];
    const float* WV = (const float*)d_in[9];
    const float* bV = (const float*)d_in[10];
    const float* Aw = (const float*)d_in[11];
    const float* VeRow = (const float*)d_in[12];

    float* out    = (float*)d_out;
    float* wV_out = out;                        // 50000*64 (numerator, then final)
    float* wE_out = out + (size_t)N_NODES * 64; // 800000*64

    float* ws    = (float*)d_ws;
    float* Q     = ws;
    float* K     = ws + 3200000;
    float* V     = ws + 6400000;
    float* denom = ws + 9600000;
    int*   wqc   = (int*)(ws + 10000000);       // work-queue counter (1 int)

    const int* src_idx = ei;
    const int* dst_idx = ei + N_EDGES;

    hipMemsetAsync(wV_out, 0, (size_t)N_NODES * 64 * sizeof(float), stream);
    hipMemsetAsync(denom, 0, (size_t)N_NODES * 8 * sizeof(float), stream);
    hipMemsetAsync(wqc, 0, sizeof(int), stream);

    qkv_kernel<<<3125, 256, 0, stream>>>(x, WQ, bQ, WK, bK, WV, bV, Q, K, V);
    edge_kernel<<<768, 256, 0, stream>>>(edge_attr, src_idx, dst_idx, WE, bE, Aw,
                                         Q, K, V, VeRow, wE_out, denom, wV_out, wqc);
    finalize_kernel<<<3125, 256, 0, stream>>>(denom, wV_out);
}

// Round 20
// 315.559 us; speedup vs baseline: 2.4657x; 2.4657x over previous
//
#include <hip/hip_runtime.h>
#include <hip/hip_bf16.h>
#include <math.h>

#define N_NODES 50000
#define N_EDGES 800000
#define CLAMP_V 5.0f

typedef short short8 __attribute__((ext_vector_type(8)));
typedef short short4v __attribute__((ext_vector_type(4)));
typedef float f32x4  __attribute__((ext_vector_type(4)));

static __device__ inline short f2bf(float x) {
    __hip_bfloat16 h = __float2bfloat16(x);   // RNE
    return __builtin_bit_cast(short, h);
}
static __device__ inline float bf2f(short s) {
    unsigned u = ((unsigned)(unsigned short)s) << 16;
    return __builtin_bit_cast(float, u);
}

// ---------------- Kernel 1: Q/K/V node projections ----------------
__global__ __launch_bounds__(256) void qkv_kernel(
    const float* __restrict__ x,
    const float* __restrict__ WQ, const float* __restrict__ bQ,
    const float* __restrict__ WK, const float* __restrict__ bK,
    const float* __restrict__ WV, const float* __restrict__ bV,
    float* __restrict__ Q, float* __restrict__ K, float* __restrict__ V)
{
    const int t = threadIdx.x;
    const int c = t & 63;
    const int nl = t >> 6;
    const int base = blockIdx.x * 16;

    float accQ[4], accK[4], accV[4];
    int nodes[4];
#pragma unroll
    for (int j = 0; j < 4; ++j) {
        nodes[j] = base + j * 4 + nl;
        accQ[j] = bQ[c]; accK[j] = bK[c]; accV[j] = bV[c];
    }
    for (int k = 0; k < 64; ++k) {
        const float wq = WQ[k * 64 + c];
        const float wk = WK[k * 64 + c];
        const float wv = WV[k * 64 + c];
#pragma unroll
        for (int j = 0; j < 4; ++j) {
            const float xv = x[nodes[j] * 64 + k];
            accQ[j] += xv * wq;
            accK[j] += xv * wk;
            accV[j] += xv * wv;
        }
    }
#pragma unroll
    for (int j = 0; j < 4; ++j) {
        const int n = nodes[j];
        Q[n * 64 + c] = accQ[j];
        K[n * 64 + c] = accK[j];
        V[n * 64 + c] = accV[j];
    }
}

// ---------------- Kernel 2: fused E-GEMM + score + denom + numerator ----------------
// Final form (R18): one-fence schedule, 3-product bf16-split MFMA E-GEMM,
// bf16 E^T transpose buffer (relative error only -> sqrt-safe), cross-
// iteration software pipeline (A-raw + indices prefetch), static stride
// schedule (optimal makespan; dynamic queue proven non-improving).
__global__ __launch_bounds__(256, 3) void edge_kernel(
    const float* __restrict__ edge_attr,
    const int* __restrict__ src_idx, const int* __restrict__ dst_idx,
    const float* __restrict__ WE, const float* __restrict__ bE,
    const float* __restrict__ Aw,
    const float* __restrict__ Qn, const float* __restrict__ Kn,
    const float* __restrict__ Vn, const float* __restrict__ VeRow,
    float* __restrict__ wE_out, float* __restrict__ denom,
    float* __restrict__ wV_num)
{
    // [0,16K)=B_hi  [16K,32K)=B_lo  [32K, +4*4160)=E^T bf16 bufs
    __shared__ __align__(16) char raw[49408];
    __shared__ float bEs[128];

    short8* Bhi = (short8*)raw;                  // [(ct*2+kh)*64 + lane]
    short8* Blo = (short8*)(raw + 16384);

    const int t = threadIdx.x;
    const int wave = t >> 6;
    const int lane = t & 63;

    // ---- init: bf16 hi/lo B-fragments from global WE
    short* BhiE = (short*)raw;
    short* BloE = (short*)(raw + 16384);
    for (int i = t; i < 8192; i += 256) {
        const int j  = i & 7;
        const int ln = (i >> 3) & 63;
        const int kh = (i >> 9) & 1;
        const int ct = i >> 10;
        const int k   = kh * 32 + ((ln >> 4) << 3) + j;
        const int col = (ct << 4) + (ln & 15);
        const float w = WE[k * 128 + col];
        const short hb = f2bf(w);
        BhiE[i] = hb;
        BloE[i] = f2bf(w - bf2f(hb));
    }
    if (t < 128) bEs[t] = bE[t];
    __syncthreads();

    unsigned short* Eb = (unsigned short*)(raw + 32768 + wave * 4160);

    const int h    = lane >> 3;
    const int kk   = lane & 7;
    const int g    = lane >> 4;
    const int c4   = lane & 15;
    const int h16k = (h << 4) + kk;
    const int ewbase = (h16k << 4) + (h << 2);          // col1 = h16k
    const int ebbase = ((h16k + 8) << 4) + (h << 2);    // col2 = h16k+8

    // loop-invariant weights in registers (global reads, once, L2-hot)
    float veR[8], awR[8];
#pragma unroll
    for (int dd = 0; dd < 8; ++dd) {
        veR[dd] = VeRow[dd * 64 + lane];
        awR[dd] = Aw[dd * 8 + h];
    }

    const int G = (int)gridDim.x;

    // pipeline state: current A-raw + indices; next A-raw + indices
    float4 arC[4], arN[4];
    int seC[16], deC[16], seN[16], deN[16];

    // ---- prologue
    int it = blockIdx.x;
    {
        const int ebase0 = __builtin_amdgcn_readfirstlane(it * 64 + wave * 16);
#pragma unroll
        for (int p = 0; p < 2; ++p) {
            const float* srcp = edge_attr + (size_t)(ebase0 + c4) * 64 + p * 32 + (g << 3);
            arC[2 * p]     = *(const float4*)srcp;
            arC[2 * p + 1] = *(const float4*)(srcp + 4);
        }
#pragma unroll
        for (int r = 0; r < 16; ++r) {
            seC[r] = src_idx[ebase0 + r];
            deC[r] = dst_idx[ebase0 + r];
        }
    }

    for (; it < 12500; it += G) {
        const int ebaseC = __builtin_amdgcn_readfirstlane(it * 64 + wave * 16);
        const int itN    = it + G;
        const int itNc   = (itN < 12500) ? itN : 0;   // clamped (unused at tail)
        const int ebaseN = __builtin_amdgcn_readfirstlane(itNc * 64 + wave * 16);

        // ---- convert A(cur) -> bf16 hi/lo (arC landed long ago; no wait)
        short8 ah[2], al[2];
#pragma unroll
        for (int p = 0; p < 2; ++p) {
            const float xv[8] = {arC[2*p].x, arC[2*p].y, arC[2*p].z, arC[2*p].w,
                                 arC[2*p+1].x, arC[2*p+1].y, arC[2*p+1].z, arC[2*p+1].w};
#pragma unroll
            for (int j = 0; j < 8; ++j) {
                const short hb = f2bf(xv[j]);
                ah[p][j] = hb;
                al[p][j] = f2bf(xv[j] - bf2f(hb));
            }
        }

        // ---- next-iteration index scalar loads (land during MFMA)
#pragma unroll
        for (int r = 0; r < 16; ++r) {
            seN[r] = src_idx[ebaseN + r];
            deN[r] = dst_idx[ebaseN + r];
        }

        // ---- gathers for CURRENT iteration (consumed in score phase)
        float vv[16], kv[16], qv[16];
#pragma unroll
        for (int r = 0; r < 16; ++r) vv[r] = Vn[seC[r] * 64 + lane];
#pragma unroll
        for (int r = 0; r < 16; ++r) {
            kv[r] = Kn[seC[r] * 64 + lane];
            qv[r] = Qn[deC[r] * 64 + lane];
        }

        // ---- A(next) raw loads: issued last, consumed at body end
#pragma unroll
        for (int p = 0; p < 2; ++p) {
            const float* srcp = edge_attr + (size_t)(ebaseN + c4) * 64 + p * 32 + (g << 3);
            arN[2 * p]     = *(const float4*)srcp;
            arN[2 * p + 1] = *(const float4*)(srcp + 4);
        }

        // ---- MFMA (3-product bf16 split — full precision)
        f32x4 acc[8] = {};
        __builtin_amdgcn_s_setprio(1);
#pragma unroll
        for (int kh = 0; kh < 2; ++kh) {
#pragma unroll
            for (int ct = 0; ct < 8; ++ct) {
                const short8 bh = Bhi[(ct * 2 + kh) * 64 + lane];
                const short8 bl = Blo[(ct * 2 + kh) * 64 + lane];
                acc[ct] = __builtin_amdgcn_mfma_f32_16x16x32_bf16(ah[kh], bh, acc[ct], 0, 0, 0);
                acc[ct] = __builtin_amdgcn_mfma_f32_16x16x32_bf16(al[kh], bh, acc[ct], 0, 0, 0);
                acc[ct] = __builtin_amdgcn_mfma_f32_16x16x32_bf16(ah[kh], bl, acc[ct], 0, 0, 0);
            }
        }
        __builtin_amdgcn_s_setprio(0);

        // ---- E^T write: ALL lanes, bf16 packed b64, then ONE fence
#pragma unroll
        for (int ct = 0; ct < 8; ++ct) {
            const int col = (ct << 4) + c4;
            const float b = bEs[col];
            short4v pk;
#pragma unroll
            for (int rr = 0; rr < 4; ++rr) pk[rr] = f2bf(acc[ct][rr] + b);
            *(short4v*)(Eb + (col << 4) + (ct << 2) + (g << 2)) = pk;
        }
        __asm__ volatile("s_waitcnt lgkmcnt(0)" ::: "memory");
        __builtin_amdgcn_sched_barrier(0);

        // ---- score: 16 independent edge chains (no intervening fences)
#pragma unroll
        for (int idx = 0; idx < 16; ++idx) {
            const int e = ebaseC + idx;
            const int d = deC[idx];
            const float kq = kv[idx] + qv[idx];
            const float ew = bf2f((short)Eb[ewbase + idx]);
            const float eb = bf2f((short)Eb[ebbase + idx]);
            float sc = kq * ew;
            sc = copysignf(sqrtf(fabsf(sc)), sc) + eb;  // signed sqrt
            wE_out[(size_t)e * 64 + lane] = sc;

            // broadcast e_t[h,dd] once; feed BOTH rsum and the logit
            float rsum = 0.f, pp = 0.f;
#pragma unroll
            for (int dd = 0; dd < 8; ++dd) {
                const float etd = __shfl(sc, (lane & 56) + dd);  // e_t[h,dd]
                rsum += etd * veR[dd];                           // VeRow[dd,h,kk]
                pp   += etd * awR[dd];                           // Aw[dd,h]
            }
            pp = fminf(fmaxf(pp, -CLAMP_V), CLAMP_V);
            const float ex = __expf(pp);
            if (kk == 0) unsafeAtomicAdd(&denom[d * 8 + h], ex);
            unsafeAtomicAdd(&wV_num[(size_t)d * 64 + lane],
                            ex * (vv[idx] + rsum));
        }
        __builtin_amdgcn_sched_barrier(0);   // next iter's E^T writes stay below

        // ---- rotate pipeline state (arN landed during MFMA+score)
#pragma unroll
        for (int p = 0; p < 4; ++p) arC[p] = arN[p];
#pragma unroll
        for (int r = 0; r < 16; ++r) { seC[r] = seN[r]; deC[r] = deN[r]; }
    }
}

// ---------------- Kernel 3: finalize — wV = numer / denom (float4) ----------------
__global__ __launch_bounds__(256) void finalize_kernel(
    const float* __restrict__ denom, float* __restrict__ wV)
{
    const int i4 = blockIdx.x * 256 + threadIdx.x;  // 3125 blocks * 256 = 800K float4
    const int base = i4 << 2;                       // 4 consecutive floats, same h-block
    const int n = base >> 6;
    const int h = (base >> 3) & 7;
    const float inv = 1.0f / (denom[n * 8 + h] + 1e-16f);
    float4 v = *(float4*)(wV + base);
    v.x *= inv; v.y *= inv; v.z *= inv; v.w *= inv;
    *(float4*)(wV + base) = v;
}

extern "C" void kernel_launch(void* const* d_in, const int* in_sizes, int n_in,
                              void* d_out, int out_size, void* d_ws, size_t ws_size,
                              hipStream_t stream) {
    const float* x         = (const float*)d_in[0];
    const float* edge_attr = (const float*)d_in[1];
    const int*   ei        = (const int*)  d_in[2];
    const float* WQ = (const float*)d_in[3];
    const float* bQ = (const float*)d_in[4];
    const float* WK = (const float*)d_in[5];
    const float* bK = (const float*)d_in[6];
    const float* WE = (const float*)d_in[7];
    const float* bE = (const float*)d_in[8];
    const float* WV = (const float*)d_in[9];
    const float* bV = (const float*)d_in[10];
    const float* Aw = (const float*)d_in[11];
    const float* VeRow = (const float*)d_in[12];

    float* out    = (float*)d_out;
    float* wV_out = out;                        // 50000*64 (numerator, then final)
    float* wE_out = out + (size_t)N_NODES * 64; // 800000*64

    float* ws    = (float*)d_ws;
    float* Q     = ws;
    float* K     = ws + 3200000;
    float* V     = ws + 6400000;
    float* denom = ws + 9600000;

    const int* src_idx = ei;
    const int* dst_idx = ei + N_EDGES;

    hipMemsetAsync(wV_out, 0, (size_t)N_NODES * 64 * sizeof(float), stream);
    hipMemsetAsync(denom, 0, (size_t)N_NODES * 8 * sizeof(float), stream);

    qkv_kernel<<<3125, 256, 0, stream>>>(x, WQ, bQ, WK, bK, WV, bV, Q, K, V);
    edge_kernel<<<768, 256, 0, stream>>>(edge_attr, src_idx, dst_idx, WE, bE, Aw,
                                         Q, K, V, VeRow, wE_out, denom, wV_out);
    finalize_kernel<<<3125, 256, 0, stream>>>(denom, wV_out);
}